// Round 4
// baseline (534.088 us; speedup 1.0000x reference)
//
#include <hip/hip_runtime.h>
#include <math.h>

#define NPTS 4096
#define MPTS 4096
#define NSTEPS 8
#define ICP_TOL 1e-6f
#define NBLK 256   // 1 block per CU -> co-residency guaranteed, barrier can't deadlock

// ws layout (floats):
//   ptgt4 = ws                       : 2*4096*4 interleaved {x,y,z,0.5*|t|^2}
//   acc   = ws + 32768               : NSTEPS*32 per-step sums
//             (per batch b at step*32+b*16: { Sp(3), Sq(3), Spq(9), sum_d(1) })
//   ctrs  = (unsigned*)(ws + 32768 + NSTEPS*32) : NSTEPS single-use barrier counters

__global__ void init_kernel(const float* __restrict__ ptgt, float* __restrict__ ws) {
    float* ptgt4 = ws;
    float* acc = ws + 2 * MPTS * 4;
    unsigned* ctrs = (unsigned*)(ws + 2 * MPTS * 4 + NSTEPS * 32);
    int gid = blockIdx.x * 256 + threadIdx.x;
    if (gid < 2 * MPTS) {
        float x = ptgt[3 * gid + 0];
        float y = ptgt[3 * gid + 1];
        float z = ptgt[3 * gid + 2];
        float4 v;
        v.x = x; v.y = y; v.z = z;
        v.w = 0.5f * (x * x + y * y + z * z);
        ((float4*)ptgt4)[gid] = v;
    }
    if (gid < NSTEPS * 32) acc[gid] = 0.f;
    if (gid < NSTEPS) ctrs[gid] = 0u;
}

// Single-use grid barrier: slot `ctr` starts at 0 (init_kernel), each block
// arrives once; all data handed across is device-scope-atomic so per-XCD L2
// staleness can't serve stale values.
__device__ __forceinline__ void grid_barrier(unsigned* ctr) {
    __syncthreads();
    if (threadIdx.x == 0) {
        __threadfence();
        __hip_atomic_fetch_add(ctr, 1u, __ATOMIC_ACQ_REL, __HIP_MEMORY_SCOPE_AGENT);
        while (__hip_atomic_load(ctr, __ATOMIC_ACQUIRE, __HIP_MEMORY_SCOPE_AGENT)
               < (unsigned)NBLK) {
            __builtin_amdgcn_s_sleep(2);
        }
    }
    __syncthreads();
}

__device__ __forceinline__ void jacobi4(float A[4][4], float V[4][4]) {
    for (int i = 0; i < 4; ++i)
        for (int j = 0; j < 4; ++j) V[i][j] = (i == j) ? 1.f : 0.f;
    for (int sweep = 0; sweep < 6; ++sweep) {
        for (int p = 0; p < 3; ++p) {
            for (int q = p + 1; q < 4; ++q) {
                float apq = A[p][q];
                if (fabsf(apq) < 1e-30f) continue;
                float theta = (A[q][q] - A[p][p]) / (2.f * apq);
                float t = 1.f / (fabsf(theta) + sqrtf(theta * theta + 1.f));
                if (theta < 0.f) t = -t;
                float c = 1.f / sqrtf(t * t + 1.f);
                float s = t * c;
                for (int k = 0; k < 4; ++k) {
                    float akp = A[k][p], akq = A[k][q];
                    A[k][p] = c * akp - s * akq;
                    A[k][q] = s * akp + c * akq;
                }
                for (int k = 0; k < 4; ++k) {
                    float apk = A[p][k], aqk = A[q][k];
                    A[p][k] = c * apk - s * aqk;
                    A[q][k] = s * apk + c * aqk;
                }
                for (int k = 0; k < 4; ++k) {
                    float vkp = V[k][p], vkq = V[k][q];
                    V[k][p] = c * vkp - s * vkq;
                    V[k][q] = s * vkp + c * vkq;
                }
            }
        }
    }
}

// 256 blocks x 256 threads, persistent. Block handles 32 source points of
// batch b = bid>>7, as two 16-point register-tile passes; wave w scans target
// slice [w*1024,(w+1)*1024). Per step: NN -> device atomics into acc[step] ->
// manual grid barrier -> every block redundantly solves the 4x4 Kabsch
// eigenproblem from the same (deterministic) global sums.
__global__ __launch_bounds__(256) void icp_main(
    const float* __restrict__ psrc, float* __restrict__ ws,
    float* __restrict__ out) {

    float* ptgt4 = ws;
    float* acc = ws + 2 * MPTS * 4;
    unsigned* ctrs = (unsigned*)(ws + 2 * MPTS * 4 + NSTEPS * 32);

    __shared__ float st[2][13];     // per batch: Rcum(9), tcum(3), err(1)
    __shared__ unsigned keys[4][16];
    __shared__ float red[16][16];
    __shared__ float convs[2];

    const int tid = threadIdx.x;
    const int bid = blockIdx.x;
    const int b = bid >> 7;             // batch (128 blocks each)
    const int n0 = (bid & 127) * 32;    // first of this block's 32 source points

    if (tid < 2) {
        st[tid][0] = 1.f; st[tid][1] = 0.f; st[tid][2] = 0.f;
        st[tid][3] = 0.f; st[tid][4] = 1.f; st[tid][5] = 0.f;
        st[tid][6] = 0.f; st[tid][7] = 0.f; st[tid][8] = 1.f;
        st[tid][9] = 0.f; st[tid][10] = 0.f; st[tid][11] = 0.f;
        st[tid][12] = 0.f;
    }
    __syncthreads();

    const int w = tid >> 6, lane = tid & 63;
    const int m0 = w * 1024 + lane;
    const float4* tpb = (const float4*)ptgt4 + ((size_t)b * MPTS + m0);

    for (int step = 0; step < NSTEPS; ++step) {
        float R00 = st[b][0], R01 = st[b][1], R02 = st[b][2];
        float R10 = st[b][3], R11 = st[b][4], R12 = st[b][5];
        float R20 = st[b][6], R21 = st[b][7], R22 = st[b][8];
        float t0 = st[b][9], t1 = st[b][10], t2 = st[b][11];

        float sacc = 0.f;   // per-component partial (tid<16 threads)

        for (int p = 0; p < 2; ++p) {
            const int np = n0 + p * 16;
            const float* ps = psrc + ((size_t)b * NPTS + np) * 3;

            float pxv[16], pyv[16], pzv[16];
#pragma unroll
            for (int i = 0; i < 16; ++i) {
                float x = ps[3 * i + 0], y = ps[3 * i + 1], z = ps[3 * i + 2];
                pxv[i] = fmaf(R00, x, fmaf(R01, y, fmaf(R02, z, t0)));
                pyv[i] = fmaf(R10, x, fmaf(R11, y, fmaf(R12, z, t1)));
                pzv[i] = fmaf(R20, x, fmaf(R21, y, fmaf(R22, z, t2)));
            }

            // s = p.t - |t|^2/2; argmax s == argmin dist
            float best[16];
            int idx[16];
#pragma unroll
            for (int i = 0; i < 16; ++i) { best[i] = -3.0e38f; idx[i] = m0; }

            float4 tc = tpb[0];
            int mreg = m0;
#pragma unroll
            for (int k = 0; k < 16; ++k) {
                float4 tnx = tpb[((k + 1) & 15) * 64];  // prefetch (wraps)
                float tx = tc.x, ty = tc.y, tz = tc.z, htn = tc.w;
#pragma unroll
                for (int i = 0; i < 16; ++i) {
                    float s = fmaf(pxv[i], tx,
                                   fmaf(pyv[i], ty, fmaf(pzv[i], tz, -htn)));
                    if (s > best[i]) { best[i] = s; idx[i] = mreg; }
                }
                mreg += 64;
                tc = tnx;
            }

            // wave argmax: order-preserving key = score hi-20 bits | (4095-m)
#pragma unroll
            for (int i = 0; i < 16; ++i) {
                unsigned ub = __float_as_uint(best[i]);
                unsigned u = (__float_as_int(best[i]) >= 0) ? (ub | 0x80000000u) : ~ub;
                unsigned key = (u & 0xFFFFF000u) | (4095u - (unsigned)idx[i]);
                for (int off = 32; off; off >>= 1) {
                    unsigned o = (unsigned)__shfl_xor((int)key, off);
                    key = key > o ? key : o;
                }
                if (lane == 0) keys[w][i] = key;
            }
            __syncthreads();

            if (tid < 16) {
                unsigned key = keys[0][tid];
                unsigned k1 = keys[1][tid], k2 = keys[2][tid], k3 = keys[3][tid];
                key = key > k1 ? key : k1;
                key = key > k2 ? key : k2;
                key = key > k3 ? key : k3;
                int m = 4095 - (int)(key & 0xFFFu);
                float4 q = ((const float4*)ptgt4)[(size_t)b * MPTS + m];
                const float* pp = psrc + ((size_t)b * NPTS + np + tid) * 3;
                float x = pp[0], y = pp[1], z = pp[2];
                float px = fmaf(R00, x, fmaf(R01, y, fmaf(R02, z, t0)));
                float py = fmaf(R10, x, fmaf(R11, y, fmaf(R12, z, t1)));
                float pz = fmaf(R20, x, fmaf(R21, y, fmaf(R22, z, t2)));
                float dx = px - q.x, dy = py - q.y, dz = pz - q.z;
                float dist = sqrtf(dx * dx + dy * dy + dz * dz);
                red[tid][0] = px; red[tid][1] = py; red[tid][2] = pz;
                red[tid][3] = q.x; red[tid][4] = q.y; red[tid][5] = q.z;
                red[tid][6] = px * q.x;  red[tid][7] = px * q.y;  red[tid][8] = px * q.z;
                red[tid][9] = py * q.x;  red[tid][10] = py * q.y; red[tid][11] = py * q.z;
                red[tid][12] = pz * q.x; red[tid][13] = pz * q.y; red[tid][14] = pz * q.z;
                red[tid][15] = dist;
            }
            __syncthreads();
            if (tid < 16) {
                float s = 0.f;
#pragma unroll
                for (int r = 0; r < 16; ++r) s += red[r][tid];
                sacc += s;
            }
            __syncthreads();   // keys/red reused next pass
        }

        if (tid < 16) atomicAdd(&acc[step * 32 + b * 16 + tid], sacc);

        grid_barrier(&ctrs[step]);

        // ---- redundant per-block Kabsch (threads 0,1 = batches 0,1) ----
        float a[16];
        float errnew = 0.f;
        if (tid < 2) {
            const float* as = acc + step * 32 + tid * 16;
            for (int i = 0; i < 16; ++i)
                a[i] = __hip_atomic_load(&as[i], __ATOMIC_RELAXED,
                                         __HIP_MEMORY_SCOPE_AGENT);
            errnew = a[15] * (1.f / NPTS);
            convs[tid] = (fabsf(errnew - st[tid][12]) < ICP_TOL) ? 1.f : 0.f;
        }
        __syncthreads();
        bool done_new = (convs[0] != 0.f) && (convs[1] != 0.f);

        if (tid < 2 && !done_new) {
            const float inv_n = 1.f / NPTS;
            float pmx = a[0] * inv_n, pmy = a[1] * inv_n, pmz = a[2] * inv_n;
            float qmx = a[3] * inv_n, qmy = a[4] * inv_n, qmz = a[5] * inv_n;
            float H[3][3];
            for (int i = 0; i < 3; ++i)
                for (int j = 0; j < 3; ++j)
                    H[i][j] = a[6 + 3 * i + j] - a[i] * a[3 + j] * inv_n;

            float Sxx = H[0][0], Sxy = H[0][1], Sxz = H[0][2];
            float Syx = H[1][0], Syy = H[1][1], Syz = H[1][2];
            float Szx = H[2][0], Szy = H[2][1], Szz = H[2][2];

            float A[4][4];
            A[0][0] = Sxx + Syy + Szz;
            A[0][1] = Syz - Szy;
            A[0][2] = Szx - Sxz;
            A[0][3] = Sxy - Syx;
            A[1][1] = Sxx - Syy - Szz;
            A[1][2] = Sxy + Syx;
            A[1][3] = Szx + Sxz;
            A[2][2] = -Sxx + Syy - Szz;
            A[2][3] = Syz + Szy;
            A[3][3] = -Sxx - Syy + Szz;
            A[1][0] = A[0][1]; A[2][0] = A[0][2]; A[3][0] = A[0][3];
            A[2][1] = A[1][2]; A[3][1] = A[1][3]; A[3][2] = A[2][3];

            float V[4][4];
            jacobi4(A, V);
            int bi = 0;
            float bv = A[0][0];
            for (int i = 1; i < 4; ++i)
                if (A[i][i] > bv) { bv = A[i][i]; bi = i; }
            float qw = V[0][bi], qx = V[1][bi], qy = V[2][bi], qz = V[3][bi];
            float nr = 1.f / sqrtf(qw * qw + qx * qx + qy * qy + qz * qz);
            qw *= nr; qx *= nr; qy *= nr; qz *= nr;

            float R00n = 1.f - 2.f * (qy * qy + qz * qz);
            float R01n = 2.f * (qx * qy - qw * qz);
            float R02n = 2.f * (qx * qz + qw * qy);
            float R10n = 2.f * (qx * qy + qw * qz);
            float R11n = 1.f - 2.f * (qx * qx + qz * qz);
            float R12n = 2.f * (qy * qz - qw * qx);
            float R20n = 2.f * (qx * qz - qw * qy);
            float R21n = 2.f * (qy * qz + qw * qx);
            float R22n = 1.f - 2.f * (qx * qx + qy * qy);

            float tx = qmx - (R00n * pmx + R01n * pmy + R02n * pmz);
            float ty = qmy - (R10n * pmx + R11n * pmy + R12n * pmz);
            float tz = qmz - (R20n * pmx + R21n * pmy + R22n * pmz);

            float C00 = st[tid][0], C01 = st[tid][1], C02 = st[tid][2];
            float C10 = st[tid][3], C11 = st[tid][4], C12 = st[tid][5];
            float C20 = st[tid][6], C21 = st[tid][7], C22 = st[tid][8];
            float T0 = st[tid][9], T1 = st[tid][10], T2 = st[tid][11];

            st[tid][0] = R00n * C00 + R01n * C10 + R02n * C20;
            st[tid][1] = R00n * C01 + R01n * C11 + R02n * C21;
            st[tid][2] = R00n * C02 + R01n * C12 + R02n * C22;
            st[tid][3] = R10n * C00 + R11n * C10 + R12n * C20;
            st[tid][4] = R10n * C01 + R11n * C11 + R12n * C21;
            st[tid][5] = R10n * C02 + R11n * C12 + R12n * C22;
            st[tid][6] = R20n * C00 + R21n * C10 + R22n * C20;
            st[tid][7] = R20n * C01 + R21n * C11 + R22n * C21;
            st[tid][8] = R20n * C02 + R21n * C12 + R22n * C22;
            st[tid][9]  = R00n * T0 + R01n * T1 + R02n * T2 + tx;
            st[tid][10] = R10n * T0 + R11n * T1 + R12n * T2 + ty;
            st[tid][11] = R20n * T0 + R21n * T1 + R22n * T2 + tz;
            st[tid][12] = errnew;
        }
        __syncthreads();
        if (done_new) break;   // deterministic & identical across all blocks
    }

    if (bid == 0 && tid < 2) {
        float r00 = st[tid][0], r01 = st[tid][1], r02 = st[tid][2];
        float r10 = st[tid][3], r11 = st[tid][4], r12 = st[tid][5];
        float r20 = st[tid][6], r21 = st[tid][7], r22 = st[tid][8];
        float qw = 0.5f * sqrtf(fmaxf(1.f + r00 + r11 + r22, 1e-12f));
        float qx = 0.5f * sqrtf(fmaxf(1.f + r00 - r11 - r22, 1e-12f));
        float qy = 0.5f * sqrtf(fmaxf(1.f - r00 + r11 - r22, 1e-12f));
        float qz = 0.5f * sqrtf(fmaxf(1.f - r00 - r11 + r22, 1e-12f));
        qx = (r21 - r12 >= 0.f) ? qx : -qx;
        qy = (r02 - r20 >= 0.f) ? qy : -qy;
        qz = (r10 - r01 >= 0.f) ? qz : -qz;
        out[tid * 7 + 0] = st[tid][9];
        out[tid * 7 + 1] = st[tid][10];
        out[tid * 7 + 2] = st[tid][11];
        out[tid * 7 + 3] = qx;
        out[tid * 7 + 4] = qy;
        out[tid * 7 + 5] = qz;
        out[tid * 7 + 6] = qw;
    }
}

extern "C" void kernel_launch(void* const* d_in, const int* in_sizes, int n_in,
                              void* d_out, int out_size, void* d_ws, size_t ws_size,
                              hipStream_t stream) {
    const float* psrc = (const float*)d_in[0];
    const float* ptgt = (const float*)d_in[1];
    float* out = (float*)d_out;
    float* ws = (float*)d_ws;

    init_kernel<<<32, 256, 0, stream>>>(ptgt, ws);
    icp_main<<<NBLK, 256, 0, stream>>>(psrc, ws, out);
}

// Round 5
// 290.344 us; speedup vs baseline: 1.8395x; 1.8395x over previous
//
#include <hip/hip_runtime.h>
#include <math.h>

#define NPTS 4096
#define MPTS 4096
#define NSTEPS 8
#define ICP_TOL 1e-6f
#define NBLK 512   // 512 blocks x 256 thr = 2 blocks/CU; launch_bounds(256,2) guarantees residency

// ws layout (floats):
//   ptgt4 = ws                 : 2*4096*4 interleaved {x,y,z,0.5*|t|^2}
//   acc   = ws + 32768         : NSTEPS*32 per-step sums
//           (per batch b at step*32+b*16: { Sp(3), Sq(3), Spq(9), sum_d(1) })
//   ctrs  = (unsigned*)(ws + 32768 + 256) : NSTEPS single-use barrier counters (line-padded)
//   flag  = ctrs + NSTEPS*32   : monotone release flag (step counter)

#define ACC_OFF (2 * MPTS * 4)
#define CTR_OFF (ACC_OFF + 256)

__global__ void init_kernel(const float* __restrict__ ptgt, float* __restrict__ ws) {
    float* ptgt4 = ws;
    float* acc = ws + ACC_OFF;
    unsigned* ctrs = (unsigned*)(ws + CTR_OFF);
    int gid = blockIdx.x * 256 + threadIdx.x;
    if (gid < 2 * MPTS) {
        float x = ptgt[3 * gid + 0];
        float y = ptgt[3 * gid + 1];
        float z = ptgt[3 * gid + 2];
        float4 v;
        v.x = x; v.y = y; v.z = z;
        v.w = 0.5f * (x * x + y * y + z * z);
        ((float4*)ptgt4)[gid] = v;
    }
    if (gid < NSTEPS * 32) acc[gid] = 0.f;
    if (gid < NSTEPS * 32 + 32) ctrs[gid] = 0u;   // counters + flag word
}

// Relaxed two-phase grid barrier. Correctness: each block's acc atomicAdds are
// drained by __syncthreads' vmcnt(0) before its ctr increment; flag is set only
// after all NBLK increments (RMW-ordered at the coherence point); spinners poll
// the flag RELAXED (agent-scope atomic loads read the coherence point; no
// per-poll L2 invalidate) and issue ONE acquire fence on exit.
__device__ __forceinline__ void grid_barrier(unsigned* ctr, unsigned* flag, unsigned gen) {
    __syncthreads();
    if (threadIdx.x == 0) {
        unsigned old = __hip_atomic_fetch_add(ctr, 1u, __ATOMIC_RELAXED,
                                              __HIP_MEMORY_SCOPE_AGENT);
        if (old == (unsigned)NBLK - 1u) {
            __hip_atomic_store(flag, gen, __ATOMIC_RELAXED, __HIP_MEMORY_SCOPE_AGENT);
        } else {
            while (__hip_atomic_load(flag, __ATOMIC_RELAXED, __HIP_MEMORY_SCOPE_AGENT) < gen) {
                __builtin_amdgcn_s_sleep(8);
            }
        }
        __builtin_amdgcn_fence(__ATOMIC_ACQUIRE, "agent");
    }
    __syncthreads();
}

__device__ __forceinline__ float frcp(float x) {
#if __has_builtin(__builtin_amdgcn_rcpf)
    return __builtin_amdgcn_rcpf(x);
#else
    return 1.f / x;
#endif
}
__device__ __forceinline__ float frsq(float x) {
#if __has_builtin(__builtin_amdgcn_rsqf)
    return __builtin_amdgcn_rsqf(x);
#else
    return 1.f / sqrtf(x);
#endif
}

__device__ __forceinline__ void jacobi4(float A[4][4], float V[4][4]) {
    for (int i = 0; i < 4; ++i)
        for (int j = 0; j < 4; ++j) V[i][j] = (i == j) ? 1.f : 0.f;
    for (int sweep = 0; sweep < 6; ++sweep) {
        float diag = fabsf(A[0][0]) + fabsf(A[1][1]) + fabsf(A[2][2]) + fabsf(A[3][3]);
        float off = fabsf(A[0][1]) + fabsf(A[0][2]) + fabsf(A[0][3])
                  + fabsf(A[1][2]) + fabsf(A[1][3]) + fabsf(A[2][3]);
        if (off < 1e-7f * diag) break;   // eigvec needs ~1e-4; this is plenty
        for (int p = 0; p < 3; ++p) {
            for (int q = p + 1; q < 4; ++q) {
                float apq = A[p][q];
                if (fabsf(apq) < 1e-30f) continue;
                float theta = (A[q][q] - A[p][p]) * 0.5f * frcp(apq);
                float ath = fabsf(theta);
                float t = frcp(ath + sqrtf(theta * theta + 1.f));
                if (theta < 0.f) t = -t;
                float c = frsq(t * t + 1.f);
                float s = t * c;
                for (int k = 0; k < 4; ++k) {
                    float akp = A[k][p], akq = A[k][q];
                    A[k][p] = c * akp - s * akq;
                    A[k][q] = s * akp + c * akq;
                }
                for (int k = 0; k < 4; ++k) {
                    float apk = A[p][k], aqk = A[q][k];
                    A[p][k] = c * apk - s * aqk;
                    A[q][k] = s * apk + c * aqk;
                }
                for (int k = 0; k < 4; ++k) {
                    float vkp = V[k][p], vkq = V[k][q];
                    V[k][p] = c * vkp - s * vkq;
                    V[k][q] = s * vkp + c * vkq;
                }
            }
        }
    }
}

// 512 blocks x 256 threads, persistent (2 blocks/CU). Block handles 16 source
// points of batch b = bid>>8; wave w scans target slice [w*1024,(w+1)*1024).
// Per step: NN -> device atomics into acc[step] -> relaxed grid barrier ->
// every block redundantly solves the 4x4 Kabsch eigenproblem (deterministic,
// identical across blocks).
__global__ __launch_bounds__(256, 2) void icp_main(
    const float* __restrict__ psrc, float* __restrict__ ws,
    float* __restrict__ out) {

    float* ptgt4 = ws;
    float* acc = ws + ACC_OFF;
    unsigned* ctrs = (unsigned*)(ws + CTR_OFF);
    unsigned* flag = ctrs + NSTEPS * 32;

    __shared__ float st[2][13];     // per batch: Rcum(9), tcum(3), err(1)
    __shared__ unsigned keys[4][16];
    __shared__ float red[16][16];
    __shared__ float convs[2];

    const int tid = threadIdx.x;
    const int bid = blockIdx.x;
    const int b = bid >> 8;             // batch (256 blocks each)
    const int n0 = (bid & 255) * 16;    // this block's 16 source points

    if (tid < 2) {
        st[tid][0] = 1.f; st[tid][1] = 0.f; st[tid][2] = 0.f;
        st[tid][3] = 0.f; st[tid][4] = 1.f; st[tid][5] = 0.f;
        st[tid][6] = 0.f; st[tid][7] = 0.f; st[tid][8] = 1.f;
        st[tid][9] = 0.f; st[tid][10] = 0.f; st[tid][11] = 0.f;
        st[tid][12] = 0.f;
    }
    __syncthreads();

    const int w = tid >> 6, lane = tid & 63;
    const int m0 = w * 1024 + lane;
    const float4* tpb = (const float4*)ptgt4 + ((size_t)b * MPTS + m0);
    const float* ps = psrc + ((size_t)b * NPTS + n0) * 3;

    for (int step = 0; step < NSTEPS; ++step) {
        float R00 = st[b][0], R01 = st[b][1], R02 = st[b][2];
        float R10 = st[b][3], R11 = st[b][4], R12 = st[b][5];
        float R20 = st[b][6], R21 = st[b][7], R22 = st[b][8];
        float t0 = st[b][9], t1 = st[b][10], t2 = st[b][11];

        float pxv[16], pyv[16], pzv[16];
#pragma unroll
        for (int i = 0; i < 16; ++i) {
            float x = ps[3 * i + 0], y = ps[3 * i + 1], z = ps[3 * i + 2];
            pxv[i] = fmaf(R00, x, fmaf(R01, y, fmaf(R02, z, t0)));
            pyv[i] = fmaf(R10, x, fmaf(R11, y, fmaf(R12, z, t1)));
            pzv[i] = fmaf(R20, x, fmaf(R21, y, fmaf(R22, z, t2)));
        }

        // s = p.t - |t|^2/2; argmax s == argmin dist. Prefetch depth 2.
        float best[16];
        int idx[16];
#pragma unroll
        for (int i = 0; i < 16; ++i) { best[i] = -3.0e38f; idx[i] = m0; }

        float4 tc0 = tpb[0];
        float4 tc1 = tpb[64];
        int mreg = m0;
#pragma unroll
        for (int k = 0; k < 16; ++k) {
            float4 tnx = tpb[((k + 2) & 15) * 64];  // wraps harmlessly
            float tx = tc0.x, ty = tc0.y, tz = tc0.z, htn = tc0.w;
#pragma unroll
            for (int i = 0; i < 16; ++i) {
                float s = fmaf(pxv[i], tx, fmaf(pyv[i], ty, fmaf(pzv[i], tz, -htn)));
                if (s > best[i]) { best[i] = s; idx[i] = mreg; }
            }
            mreg += 64;
            tc0 = tc1;
            tc1 = tnx;
        }

        // wave argmax via order-preserving packed key: score hi-20 | (4095-m)
#pragma unroll
        for (int i = 0; i < 16; ++i) {
            unsigned ub = __float_as_uint(best[i]);
            unsigned u = (__float_as_int(best[i]) >= 0) ? (ub | 0x80000000u) : ~ub;
            unsigned key = (u & 0xFFFFF000u) | (4095u - (unsigned)idx[i]);
            for (int off = 32; off; off >>= 1) {
                unsigned o = (unsigned)__shfl_xor((int)key, off);
                key = key > o ? key : o;
            }
            if (lane == 0) keys[w][i] = key;
        }
        __syncthreads();

        if (tid < 16) {
            unsigned key = keys[0][tid];
            unsigned k1 = keys[1][tid], k2 = keys[2][tid], k3 = keys[3][tid];
            key = key > k1 ? key : k1;
            key = key > k2 ? key : k2;
            key = key > k3 ? key : k3;
            int m = 4095 - (int)(key & 0xFFFu);
            float4 q = ((const float4*)ptgt4)[(size_t)b * MPTS + m];
            const float* pp = psrc + ((size_t)b * NPTS + n0 + tid) * 3;
            float x = pp[0], y = pp[1], z = pp[2];
            float px = fmaf(R00, x, fmaf(R01, y, fmaf(R02, z, t0)));
            float py = fmaf(R10, x, fmaf(R11, y, fmaf(R12, z, t1)));
            float pz = fmaf(R20, x, fmaf(R21, y, fmaf(R22, z, t2)));
            float dx = px - q.x, dy = py - q.y, dz = pz - q.z;
            float dist = sqrtf(dx * dx + dy * dy + dz * dz);
            red[tid][0] = px; red[tid][1] = py; red[tid][2] = pz;
            red[tid][3] = q.x; red[tid][4] = q.y; red[tid][5] = q.z;
            red[tid][6] = px * q.x;  red[tid][7] = px * q.y;  red[tid][8] = px * q.z;
            red[tid][9] = py * q.x;  red[tid][10] = py * q.y; red[tid][11] = py * q.z;
            red[tid][12] = pz * q.x; red[tid][13] = pz * q.y; red[tid][14] = pz * q.z;
            red[tid][15] = dist;
        }
        __syncthreads();
        if (tid < 16) {
            float s = 0.f;
#pragma unroll
            for (int r = 0; r < 16; ++r) s += red[r][tid];
            atomicAdd(&acc[step * 32 + b * 16 + tid], s);
        }

        grid_barrier(&ctrs[step * 32], flag, (unsigned)(step + 1));

        // ---- redundant per-block Kabsch (threads 0,1 = batches 0,1) ----
        float a[16];
        float errnew = 0.f;
        if (tid < 2) {
            const float* as = acc + step * 32 + tid * 16;
            for (int i = 0; i < 16; ++i)
                a[i] = __hip_atomic_load(&as[i], __ATOMIC_RELAXED,
                                         __HIP_MEMORY_SCOPE_AGENT);
            errnew = a[15] * (1.f / NPTS);
            convs[tid] = (fabsf(errnew - st[tid][12]) < ICP_TOL) ? 1.f : 0.f;
        }
        __syncthreads();
        bool done_new = (convs[0] != 0.f) && (convs[1] != 0.f);

        if (tid < 2 && !done_new) {
            const float inv_n = 1.f / NPTS;
            float pmx = a[0] * inv_n, pmy = a[1] * inv_n, pmz = a[2] * inv_n;
            float qmx = a[3] * inv_n, qmy = a[4] * inv_n, qmz = a[5] * inv_n;
            float H[3][3];
            for (int i = 0; i < 3; ++i)
                for (int j = 0; j < 3; ++j)
                    H[i][j] = a[6 + 3 * i + j] - a[i] * a[3 + j] * inv_n;

            float Sxx = H[0][0], Sxy = H[0][1], Sxz = H[0][2];
            float Syx = H[1][0], Syy = H[1][1], Syz = H[1][2];
            float Szx = H[2][0], Szy = H[2][1], Szz = H[2][2];

            float A[4][4];
            A[0][0] = Sxx + Syy + Szz;
            A[0][1] = Syz - Szy;
            A[0][2] = Szx - Sxz;
            A[0][3] = Sxy - Syx;
            A[1][1] = Sxx - Syy - Szz;
            A[1][2] = Sxy + Syx;
            A[1][3] = Szx + Sxz;
            A[2][2] = -Sxx + Syy - Szz;
            A[2][3] = Syz + Szy;
            A[3][3] = -Sxx - Syy + Szz;
            A[1][0] = A[0][1]; A[2][0] = A[0][2]; A[3][0] = A[0][3];
            A[2][1] = A[1][2]; A[3][1] = A[1][3]; A[3][2] = A[2][3];

            float V[4][4];
            jacobi4(A, V);
            int bi = 0;
            float bv = A[0][0];
            for (int i = 1; i < 4; ++i)
                if (A[i][i] > bv) { bv = A[i][i]; bi = i; }
            float qw = V[0][bi], qx = V[1][bi], qy = V[2][bi], qz = V[3][bi];
            float nr = frsq(qw * qw + qx * qx + qy * qy + qz * qz);
            qw *= nr; qx *= nr; qy *= nr; qz *= nr;

            float R00n = 1.f - 2.f * (qy * qy + qz * qz);
            float R01n = 2.f * (qx * qy - qw * qz);
            float R02n = 2.f * (qx * qz + qw * qy);
            float R10n = 2.f * (qx * qy + qw * qz);
            float R11n = 1.f - 2.f * (qx * qx + qz * qz);
            float R12n = 2.f * (qy * qz - qw * qx);
            float R20n = 2.f * (qx * qz - qw * qy);
            float R21n = 2.f * (qy * qz + qw * qx);
            float R22n = 1.f - 2.f * (qx * qx + qy * qy);

            float tx = qmx - (R00n * pmx + R01n * pmy + R02n * pmz);
            float ty = qmy - (R10n * pmx + R11n * pmy + R12n * pmz);
            float tz = qmz - (R20n * pmx + R21n * pmy + R22n * pmz);

            float C00 = st[tid][0], C01 = st[tid][1], C02 = st[tid][2];
            float C10 = st[tid][3], C11 = st[tid][4], C12 = st[tid][5];
            float C20 = st[tid][6], C21 = st[tid][7], C22 = st[tid][8];
            float T0 = st[tid][9], T1 = st[tid][10], T2 = st[tid][11];

            st[tid][0] = R00n * C00 + R01n * C10 + R02n * C20;
            st[tid][1] = R00n * C01 + R01n * C11 + R02n * C21;
            st[tid][2] = R00n * C02 + R01n * C12 + R02n * C22;
            st[tid][3] = R10n * C00 + R11n * C10 + R12n * C20;
            st[tid][4] = R10n * C01 + R11n * C11 + R12n * C21;
            st[tid][5] = R10n * C02 + R11n * C12 + R12n * C22;
            st[tid][6] = R20n * C00 + R21n * C10 + R22n * C20;
            st[tid][7] = R20n * C01 + R21n * C11 + R22n * C21;
            st[tid][8] = R20n * C02 + R21n * C12 + R22n * C22;
            st[tid][9]  = R00n * T0 + R01n * T1 + R02n * T2 + tx;
            st[tid][10] = R10n * T0 + R11n * T1 + R12n * T2 + ty;
            st[tid][11] = R20n * T0 + R21n * T1 + R22n * T2 + tz;
            st[tid][12] = errnew;
        }
        __syncthreads();
        if (done_new) break;   // deterministic & identical across all blocks
    }

    if (bid == 0 && tid < 2) {
        float r00 = st[tid][0], r01 = st[tid][1], r02 = st[tid][2];
        float r10 = st[tid][3], r11 = st[tid][4], r12 = st[tid][5];
        float r20 = st[tid][6], r21 = st[tid][7], r22 = st[tid][8];
        float qw = 0.5f * sqrtf(fmaxf(1.f + r00 + r11 + r22, 1e-12f));
        float qx = 0.5f * sqrtf(fmaxf(1.f + r00 - r11 - r22, 1e-12f));
        float qy = 0.5f * sqrtf(fmaxf(1.f - r00 + r11 - r22, 1e-12f));
        float qz = 0.5f * sqrtf(fmaxf(1.f - r00 - r11 + r22, 1e-12f));
        qx = (r21 - r12 >= 0.f) ? qx : -qx;
        qy = (r02 - r20 >= 0.f) ? qy : -qy;
        qz = (r10 - r01 >= 0.f) ? qz : -qz;
        out[tid * 7 + 0] = st[tid][9];
        out[tid * 7 + 1] = st[tid][10];
        out[tid * 7 + 2] = st[tid][11];
        out[tid * 7 + 3] = qx;
        out[tid * 7 + 4] = qy;
        out[tid * 7 + 5] = qz;
        out[tid * 7 + 6] = qw;
    }
}

extern "C" void kernel_launch(void* const* d_in, const int* in_sizes, int n_in,
                              void* d_out, int out_size, void* d_ws, size_t ws_size,
                              hipStream_t stream) {
    const float* psrc = (const float*)d_in[0];
    const float* ptgt = (const float*)d_in[1];
    float* out = (float*)d_out;
    float* ws = (float*)d_ws;

    init_kernel<<<32, 256, 0, stream>>>(ptgt, ws);
    icp_main<<<NBLK, 256, 0, stream>>>(psrc, ws, out);
}

// Round 6
// 275.288 us; speedup vs baseline: 1.9401x; 1.0547x over previous
//
#include <hip/hip_runtime.h>
#include <math.h>

#define NPTS 4096
#define MPTS 4096
#define NSTEPS 8
#define ICP_TOL 1e-6f
#define NBLK 512    // 2 blocks/CU, residency guaranteed by __launch_bounds__(256,2)
#define NSLOT 32    // accumulator striping slots per batch (distinct cachelines)
#define NSUB 8      // barrier arrival sub-counters

// ws layout (floats):
//   ptgt4 : [0, 32768)            interleaved {x,y,z,0.5*|t|^2} for 2*4096 targets
//   acc   : [32768, 40960)        [step][batch][slot][16] partial sums
//   ctrs  : words at float off 40960: per step 160 words
//             (8 sub-counters at sub*16, master at 128), flag word at NSTEPS*160
#define ACC_OFF 32768
#define CTR_OFF 40960
#define CTR_WORDS (NSTEPS * 160 + 16)

__global__ void init_kernel(const float* __restrict__ ptgt, float* __restrict__ ws) {
    float* ptgt4 = ws;
    float* acc = ws + ACC_OFF;
    unsigned* ctrs = (unsigned*)(ws + CTR_OFF);
    int gid = blockIdx.x * 256 + threadIdx.x;   // 8192 threads
    if (gid < 2 * MPTS) {
        float x = ptgt[3 * gid + 0];
        float y = ptgt[3 * gid + 1];
        float z = ptgt[3 * gid + 2];
        float4 v;
        v.x = x; v.y = y; v.z = z;
        v.w = 0.5f * (x * x + y * y + z * z);
        ((float4*)ptgt4)[gid] = v;
    }
    if (gid < NSTEPS * 2 * NSLOT * 16) acc[gid] = 0.f;   // 8192 floats
    if (gid < CTR_WORDS) ctrs[gid] = 0u;
}

// Two-level relaxed grid barrier (single-use counters per step; monotone flag).
// Release fence before arrival orders this block's acc atomics; acquire fence
// after the spin; spinners poll the flag RELAXED at agent scope (reads the
// coherence point; no per-poll L2 maintenance).
__device__ __forceinline__ void grid_barrier(unsigned* stepc, unsigned* flag,
                                             unsigned gen, int bid) {
    __syncthreads();
    if (threadIdx.x == 0) {
        __builtin_amdgcn_fence(__ATOMIC_RELEASE, "agent");
        unsigned* sub = stepc + (bid & (NSUB - 1)) * 16;
        unsigned old = __hip_atomic_fetch_add(sub, 1u, __ATOMIC_RELAXED,
                                              __HIP_MEMORY_SCOPE_AGENT);
        if (old == (unsigned)(NBLK / NSUB) - 1u) {
            unsigned o2 = __hip_atomic_fetch_add(stepc + 128, 1u, __ATOMIC_RELAXED,
                                                 __HIP_MEMORY_SCOPE_AGENT);
            if (o2 == (unsigned)NSUB - 1u)
                __hip_atomic_store(flag, gen, __ATOMIC_RELAXED,
                                   __HIP_MEMORY_SCOPE_AGENT);
        }
        while (__hip_atomic_load(flag, __ATOMIC_RELAXED,
                                 __HIP_MEMORY_SCOPE_AGENT) < gen) {
            __builtin_amdgcn_s_sleep(1);
        }
        __builtin_amdgcn_fence(__ATOMIC_ACQUIRE, "agent");
    }
    __syncthreads();
}

__device__ __forceinline__ float frcp(float x) {
#if __has_builtin(__builtin_amdgcn_rcpf)
    return __builtin_amdgcn_rcpf(x);
#else
    return 1.f / x;
#endif
}
__device__ __forceinline__ float frsq(float x) {
#if __has_builtin(__builtin_amdgcn_rsqf)
    return __builtin_amdgcn_rsqf(x);
#else
    return 1.f / sqrtf(x);
#endif
}

__device__ __forceinline__ void jacobi4(float A[4][4], float V[4][4]) {
    for (int i = 0; i < 4; ++i)
        for (int j = 0; j < 4; ++j) V[i][j] = (i == j) ? 1.f : 0.f;
    for (int sweep = 0; sweep < 5; ++sweep) {
        float diag = fabsf(A[0][0]) + fabsf(A[1][1]) + fabsf(A[2][2]) + fabsf(A[3][3]);
        float off = fabsf(A[0][1]) + fabsf(A[0][2]) + fabsf(A[0][3])
                  + fabsf(A[1][2]) + fabsf(A[1][3]) + fabsf(A[2][3]);
        if (off < 1e-6f * diag) break;   // eigvec needs ~1e-4; plenty
        for (int p = 0; p < 3; ++p) {
            for (int q = p + 1; q < 4; ++q) {
                float apq = A[p][q];
                if (fabsf(apq) < 1e-30f) continue;
                float theta = (A[q][q] - A[p][p]) * 0.5f * frcp(apq);
                float t = frcp(fabsf(theta) + sqrtf(theta * theta + 1.f));
                if (theta < 0.f) t = -t;
                float c = frsq(t * t + 1.f);
                float s = t * c;
                for (int k = 0; k < 4; ++k) {
                    float akp = A[k][p], akq = A[k][q];
                    A[k][p] = c * akp - s * akq;
                    A[k][q] = s * akp + c * akq;
                }
                for (int k = 0; k < 4; ++k) {
                    float apk = A[p][k], aqk = A[q][k];
                    A[p][k] = c * apk - s * aqk;
                    A[q][k] = s * apk + c * aqk;
                }
                for (int k = 0; k < 4; ++k) {
                    float vkp = V[k][p], vkq = V[k][q];
                    V[k][p] = c * vkp - s * vkq;
                    V[k][q] = s * vkp + c * vkq;
                }
            }
        }
    }
}

#define FOR16(OP) OP(0) OP(1) OP(2) OP(3) OP(4) OP(5) OP(6) OP(7) \
                  OP(8) OP(9) OP(10) OP(11) OP(12) OP(13) OP(14) OP(15)

// 512 blocks x 256 threads, persistent (2 blocks/CU). Block handles 16 source
// points of batch b = bid>>8 (named-scalar registers; no indexed arrays); wave
// w scans target slice [w*1024,(w+1)*1024), one float4 target per lane per
// iter. Per step: NN -> striped atomics -> two-level grid barrier -> every
// block redundantly gathers the slot sums + solves the 4x4 Kabsch
// eigenproblem (bit-identical across blocks).
__global__ __launch_bounds__(256, 2) void icp_main(
    const float* __restrict__ psrc, float* __restrict__ ws,
    float* __restrict__ out) {

    float* ptgt4 = ws;
    float* acc = ws + ACC_OFF;
    unsigned* ctrs = (unsigned*)(ws + CTR_OFF);
    unsigned* flag = ctrs + NSTEPS * 160;

    __shared__ float st[2][13];     // per batch: Rcum(9), tcum(3), err(1)
    __shared__ unsigned keys[4][16];
    __shared__ float red[16][16];
    __shared__ float asum[2][16];
    __shared__ float convs[2];

    const int tid = threadIdx.x;
    const int bid = blockIdx.x;
    const int b = bid >> 8;             // batch (256 blocks each)
    const int n0 = (bid & 255) * 16;    // this block's 16 source points

    if (tid < 2) {
        st[tid][0] = 1.f; st[tid][1] = 0.f; st[tid][2] = 0.f;
        st[tid][3] = 0.f; st[tid][4] = 1.f; st[tid][5] = 0.f;
        st[tid][6] = 0.f; st[tid][7] = 0.f; st[tid][8] = 1.f;
        st[tid][9] = 0.f; st[tid][10] = 0.f; st[tid][11] = 0.f;
        st[tid][12] = 0.f;
    }
    __syncthreads();

    const int w = tid >> 6, lane = tid & 63;
    const int m0 = w * 1024 + lane;
    const float4* tpb = (const float4*)ptgt4 + ((size_t)b * MPTS + m0);
    const float* ps = psrc + ((size_t)b * NPTS + n0) * 3;

    for (int step = 0; step < NSTEPS; ++step) {
        float R00 = st[b][0], R01 = st[b][1], R02 = st[b][2];
        float R10 = st[b][3], R11 = st[b][4], R12 = st[b][5];
        float R20 = st[b][6], R21 = st[b][7], R22 = st[b][8];
        float t0 = st[b][9], t1 = st[b][10], t2 = st[b][11];

        // 16 transformed source points in named registers
#define DECLP(i) float px##i, py##i, pz##i;
        FOR16(DECLP)
#undef DECLP
#define LOADP(i) { float x = ps[3*(i)], y = ps[3*(i)+1], z = ps[3*(i)+2]; \
        px##i = fmaf(R00, x, fmaf(R01, y, fmaf(R02, z, t0))); \
        py##i = fmaf(R10, x, fmaf(R11, y, fmaf(R12, z, t1))); \
        pz##i = fmaf(R20, x, fmaf(R21, y, fmaf(R22, z, t2))); }
        FOR16(LOADP)
#undef LOADP

        // s = p.t - |t|^2/2; argmax s == argmin dist (strict > keeps first max)
#define DECLB(i) float bs##i = -3.0e38f; int ix##i = m0;
        FOR16(DECLB)
#undef DECLB

        float4 tc0 = tpb[0];
        float4 tc1 = tpb[64];
        int mreg = m0;
#pragma unroll
        for (int k = 0; k < 16; ++k) {
            float4 tnx = tpb[((k + 2) & 15) * 64];  // wraps harmlessly
            float tx = tc0.x, ty = tc0.y, tz = tc0.z, htn = tc0.w;
#define PAIR(i) { float s = fmaf(px##i, tx, fmaf(py##i, ty, fmaf(pz##i, tz, -htn))); \
            if (s > bs##i) { bs##i = s; ix##i = mreg; } }
            FOR16(PAIR)
#undef PAIR
            mreg += 64;
            tc0 = tc1;
            tc1 = tnx;
        }

        // wave argmax via order-preserving packed key: score hi-20 | (4095-m)
#define REDKEY(i) { unsigned ub = __float_as_uint(bs##i); \
        unsigned u = ((int)ub >= 0) ? (ub | 0x80000000u) : ~ub; \
        unsigned key = (u & 0xFFFFF000u) | (4095u - (unsigned)ix##i); \
        for (int off = 32; off; off >>= 1) { \
            unsigned o = (unsigned)__shfl_xor((int)key, off); \
            key = key > o ? key : o; } \
        if (lane == 0) keys[w][i] = key; }
        FOR16(REDKEY)
#undef REDKEY
        __syncthreads();

        if (tid < 16) {
            unsigned key = keys[0][tid];
            unsigned k1 = keys[1][tid], k2 = keys[2][tid], k3 = keys[3][tid];
            key = key > k1 ? key : k1;
            key = key > k2 ? key : k2;
            key = key > k3 ? key : k3;
            int m = 4095 - (int)(key & 0xFFFu);
            float4 q = ((const float4*)ptgt4)[(size_t)b * MPTS + m];
            const float* pp = psrc + ((size_t)b * NPTS + n0 + tid) * 3;
            float x = pp[0], y = pp[1], z = pp[2];
            float px = fmaf(R00, x, fmaf(R01, y, fmaf(R02, z, t0)));
            float py = fmaf(R10, x, fmaf(R11, y, fmaf(R12, z, t1)));
            float pz = fmaf(R20, x, fmaf(R21, y, fmaf(R22, z, t2)));
            float dx = px - q.x, dy = py - q.y, dz = pz - q.z;
            float dist = sqrtf(dx * dx + dy * dy + dz * dz);
            red[tid][0] = px; red[tid][1] = py; red[tid][2] = pz;
            red[tid][3] = q.x; red[tid][4] = q.y; red[tid][5] = q.z;
            red[tid][6] = px * q.x;  red[tid][7] = px * q.y;  red[tid][8] = px * q.z;
            red[tid][9] = py * q.x;  red[tid][10] = py * q.y; red[tid][11] = py * q.z;
            red[tid][12] = pz * q.x; red[tid][13] = pz * q.y; red[tid][14] = pz * q.z;
            red[tid][15] = dist;
        }
        __syncthreads();
        if (tid < 16) {
            float s = 0.f;
#pragma unroll
            for (int r = 0; r < 16; ++r) s += red[r][tid];
            // striped: each block adds into slot (bid&31) -> 32 distinct lines/batch
            atomicAdd(&acc[(((size_t)step * 2 + b) * NSLOT + (bid & (NSLOT - 1))) * 16 + tid], s);
        }

        grid_barrier(ctrs + step * 160, flag, (unsigned)(step + 1), bid);

        // ---- gather slot sums (32 threads), then redundant per-block Kabsch ----
        if (tid < 32) {
            int bb = tid >> 4, c = tid & 15;
            const float* base = acc + (((size_t)step * 2 + bb) * NSLOT) * 16 + c;
            float s = 0.f;
#pragma unroll
            for (int sl = 0; sl < NSLOT; ++sl)
                s += __hip_atomic_load(base + sl * 16, __ATOMIC_RELAXED,
                                       __HIP_MEMORY_SCOPE_AGENT);
            asum[bb][c] = s;
        }
        __syncthreads();

        float a[16];
        float errnew = 0.f;
        if (tid < 2) {
            for (int i = 0; i < 16; ++i) a[i] = asum[tid][i];
            errnew = a[15] * (1.f / NPTS);
            convs[tid] = (fabsf(errnew - st[tid][12]) < ICP_TOL) ? 1.f : 0.f;
        }
        __syncthreads();
        bool done_new = (convs[0] != 0.f) && (convs[1] != 0.f);

        if (tid < 2 && !done_new) {
            const float inv_n = 1.f / NPTS;
            float pmx = a[0] * inv_n, pmy = a[1] * inv_n, pmz = a[2] * inv_n;
            float qmx = a[3] * inv_n, qmy = a[4] * inv_n, qmz = a[5] * inv_n;
            float H[3][3];
            for (int i = 0; i < 3; ++i)
                for (int j = 0; j < 3; ++j)
                    H[i][j] = a[6 + 3 * i + j] - a[i] * a[3 + j] * inv_n;

            float Sxx = H[0][0], Sxy = H[0][1], Sxz = H[0][2];
            float Syx = H[1][0], Syy = H[1][1], Syz = H[1][2];
            float Szx = H[2][0], Szy = H[2][1], Szz = H[2][2];

            float A[4][4];
            A[0][0] = Sxx + Syy + Szz;
            A[0][1] = Syz - Szy;
            A[0][2] = Szx - Sxz;
            A[0][3] = Sxy - Syx;
            A[1][1] = Sxx - Syy - Szz;
            A[1][2] = Sxy + Syx;
            A[1][3] = Szx + Sxz;
            A[2][2] = -Sxx + Syy - Szz;
            A[2][3] = Syz + Szy;
            A[3][3] = -Sxx - Syy + Szz;
            A[1][0] = A[0][1]; A[2][0] = A[0][2]; A[3][0] = A[0][3];
            A[2][1] = A[1][2]; A[3][1] = A[1][3]; A[3][2] = A[2][3];

            float V[4][4];
            jacobi4(A, V);
            int bi = 0;
            float bv = A[0][0];
            for (int i = 1; i < 4; ++i)
                if (A[i][i] > bv) { bv = A[i][i]; bi = i; }
            float qw = V[0][bi], qx = V[1][bi], qy = V[2][bi], qz = V[3][bi];
            float nr = frsq(qw * qw + qx * qx + qy * qy + qz * qz);
            qw *= nr; qx *= nr; qy *= nr; qz *= nr;

            float R00n = 1.f - 2.f * (qy * qy + qz * qz);
            float R01n = 2.f * (qx * qy - qw * qz);
            float R02n = 2.f * (qx * qz + qw * qy);
            float R10n = 2.f * (qx * qy + qw * qz);
            float R11n = 1.f - 2.f * (qx * qx + qz * qz);
            float R12n = 2.f * (qy * qz - qw * qx);
            float R20n = 2.f * (qx * qz - qw * qy);
            float R21n = 2.f * (qy * qz + qw * qx);
            float R22n = 1.f - 2.f * (qx * qx + qy * qy);

            float tx = qmx - (R00n * pmx + R01n * pmy + R02n * pmz);
            float ty = qmy - (R10n * pmx + R11n * pmy + R12n * pmz);
            float tz = qmz - (R20n * pmx + R21n * pmy + R22n * pmz);

            float C00 = st[tid][0], C01 = st[tid][1], C02 = st[tid][2];
            float C10 = st[tid][3], C11 = st[tid][4], C12 = st[tid][5];
            float C20 = st[tid][6], C21 = st[tid][7], C22 = st[tid][8];
            float T0 = st[tid][9], T1 = st[tid][10], T2 = st[tid][11];

            st[tid][0] = R00n * C00 + R01n * C10 + R02n * C20;
            st[tid][1] = R00n * C01 + R01n * C11 + R02n * C21;
            st[tid][2] = R00n * C02 + R01n * C12 + R02n * C22;
            st[tid][3] = R10n * C00 + R11n * C10 + R12n * C20;
            st[tid][4] = R10n * C01 + R11n * C11 + R12n * C21;
            st[tid][5] = R10n * C02 + R11n * C12 + R12n * C22;
            st[tid][6] = R20n * C00 + R21n * C10 + R22n * C20;
            st[tid][7] = R20n * C01 + R21n * C11 + R22n * C21;
            st[tid][8] = R20n * C02 + R21n * C12 + R22n * C22;
            st[tid][9]  = R00n * T0 + R01n * T1 + R02n * T2 + tx;
            st[tid][10] = R10n * T0 + R11n * T1 + R12n * T2 + ty;
            st[tid][11] = R20n * T0 + R21n * T1 + R22n * T2 + tz;
            st[tid][12] = errnew;
        }
        __syncthreads();
        if (done_new) break;   // bit-identical decision across all blocks
    }

    if (bid == 0 && tid < 2) {
        float r00 = st[tid][0], r01 = st[tid][1], r02 = st[tid][2];
        float r10 = st[tid][3], r11 = st[tid][4], r12 = st[tid][5];
        float r20 = st[tid][6], r21 = st[tid][7], r22 = st[tid][8];
        float qw = 0.5f * sqrtf(fmaxf(1.f + r00 + r11 + r22, 1e-12f));
        float qx = 0.5f * sqrtf(fmaxf(1.f + r00 - r11 - r22, 1e-12f));
        float qy = 0.5f * sqrtf(fmaxf(1.f - r00 + r11 - r22, 1e-12f));
        float qz = 0.5f * sqrtf(fmaxf(1.f - r00 - r11 + r22, 1e-12f));
        qx = (r21 - r12 >= 0.f) ? qx : -qx;
        qy = (r02 - r20 >= 0.f) ? qy : -qy;
        qz = (r10 - r01 >= 0.f) ? qz : -qz;
        out[tid * 7 + 0] = st[tid][9];
        out[tid * 7 + 1] = st[tid][10];
        out[tid * 7 + 2] = st[tid][11];
        out[tid * 7 + 3] = qx;
        out[tid * 7 + 4] = qy;
        out[tid * 7 + 5] = qz;
        out[tid * 7 + 6] = qw;
    }
}

extern "C" void kernel_launch(void* const* d_in, const int* in_sizes, int n_in,
                              void* d_out, int out_size, void* d_ws, size_t ws_size,
                              hipStream_t stream) {
    const float* psrc = (const float*)d_in[0];
    const float* ptgt = (const float*)d_in[1];
    float* out = (float*)d_out;
    float* ws = (float*)d_ws;

    init_kernel<<<32, 256, 0, stream>>>(ptgt, ws);
    icp_main<<<NBLK, 256, 0, stream>>>(psrc, ws, out);
}

// Round 7
// 242.535 us; speedup vs baseline: 2.2021x; 1.1350x over previous
//
#include <hip/hip_runtime.h>
#include <math.h>

#define NPTS 4096
#define MPTS 4096
#define NSTEPS 8
#define ICP_TOL 1e-6f
#define NBLK 512    // 2 blocks/CU, residency guaranteed by __launch_bounds__(256,2)
#define NSLOT 32    // accumulator striping slots per batch (distinct cachelines)
#define NSUB 8      // barrier arrival sub-counters

// ws layout (floats):
//   ptgt4 : [0, 32768)            interleaved {x,y,z,0.5*|t|^2} for 2*4096 targets
//   acc   : [32768, 40960)        [step][batch][slot][16] partial sums
//   ctrs  : words at float off 40960: per step 160 words
//             (8 sub-counters at sub*16, master at 128), flag word at NSTEPS*160
#define ACC_OFF 32768
#define CTR_OFF 40960
#define CTR_WORDS (NSTEPS * 160 + 16)

__global__ void init_kernel(const float* __restrict__ ptgt, float* __restrict__ ws) {
    float* ptgt4 = ws;
    float* acc = ws + ACC_OFF;
    unsigned* ctrs = (unsigned*)(ws + CTR_OFF);
    int gid = blockIdx.x * 256 + threadIdx.x;   // 8192 threads
    if (gid < 2 * MPTS) {
        float x = ptgt[3 * gid + 0];
        float y = ptgt[3 * gid + 1];
        float z = ptgt[3 * gid + 2];
        float4 v;
        v.x = x; v.y = y; v.z = z;
        v.w = 0.5f * (x * x + y * y + z * z);
        ((float4*)ptgt4)[gid] = v;
    }
    if (gid < NSTEPS * 2 * NSLOT * 16) acc[gid] = 0.f;   // 8192 floats
    if (gid < CTR_WORDS) ctrs[gid] = 0u;
}

// FENCE-FREE two-level grid barrier (single-use counters per step; monotone
// flag). Correctness without fences: ALL cross-block data (acc, counters,
// flag) moves through agent-scope atomics, which operate at the coherence
// point and bypass the non-coherent per-XCD L2s (empirically proven by the
// R5/R6 spin observing remote flag stores with RELAXED loads). Ordering:
// __syncthreads() drains vmcnt(0), so this block's acc atomicAdds are ack'd
// at the coherence point before the arrival RMW issues; consumers read acc
// only after the barrier (program order after s_barrier).
__device__ __forceinline__ void grid_barrier(unsigned* stepc, unsigned* flag,
                                             unsigned gen, int bid) {
    __syncthreads();
    if (threadIdx.x == 0) {
        unsigned* sub = stepc + (bid & (NSUB - 1)) * 16;
        unsigned old = __hip_atomic_fetch_add(sub, 1u, __ATOMIC_RELAXED,
                                              __HIP_MEMORY_SCOPE_AGENT);
        if (old == (unsigned)(NBLK / NSUB) - 1u) {
            unsigned o2 = __hip_atomic_fetch_add(stepc + 128, 1u, __ATOMIC_RELAXED,
                                                 __HIP_MEMORY_SCOPE_AGENT);
            if (o2 == (unsigned)NSUB - 1u)
                __hip_atomic_store(flag, gen, __ATOMIC_RELAXED,
                                   __HIP_MEMORY_SCOPE_AGENT);
        }
        while (__hip_atomic_load(flag, __ATOMIC_RELAXED,
                                 __HIP_MEMORY_SCOPE_AGENT) < gen) {
            __builtin_amdgcn_s_sleep(1);
        }
    }
    __syncthreads();
}

__device__ __forceinline__ float frcp(float x) {
#if __has_builtin(__builtin_amdgcn_rcpf)
    return __builtin_amdgcn_rcpf(x);
#else
    return 1.f / x;
#endif
}
__device__ __forceinline__ float frsq(float x) {
#if __has_builtin(__builtin_amdgcn_rsqf)
    return __builtin_amdgcn_rsqf(x);
#else
    return 1.f / sqrtf(x);
#endif
}

__device__ __forceinline__ void jacobi4(float A[4][4], float V[4][4]) {
    for (int i = 0; i < 4; ++i)
        for (int j = 0; j < 4; ++j) V[i][j] = (i == j) ? 1.f : 0.f;
    for (int sweep = 0; sweep < 5; ++sweep) {
        float diag = fabsf(A[0][0]) + fabsf(A[1][1]) + fabsf(A[2][2]) + fabsf(A[3][3]);
        float off = fabsf(A[0][1]) + fabsf(A[0][2]) + fabsf(A[0][3])
                  + fabsf(A[1][2]) + fabsf(A[1][3]) + fabsf(A[2][3]);
        if (off < 1e-6f * diag) break;   // eigvec needs ~1e-4; plenty
        for (int p = 0; p < 3; ++p) {
            for (int q = p + 1; q < 4; ++q) {
                float apq = A[p][q];
                if (fabsf(apq) < 1e-30f) continue;
                float theta = (A[q][q] - A[p][p]) * 0.5f * frcp(apq);
                float t = frcp(fabsf(theta) + sqrtf(theta * theta + 1.f));
                if (theta < 0.f) t = -t;
                float c = frsq(t * t + 1.f);
                float s = t * c;
                for (int k = 0; k < 4; ++k) {
                    float akp = A[k][p], akq = A[k][q];
                    A[k][p] = c * akp - s * akq;
                    A[k][q] = s * akp + c * akq;
                }
                for (int k = 0; k < 4; ++k) {
                    float apk = A[p][k], aqk = A[q][k];
                    A[p][k] = c * apk - s * aqk;
                    A[q][k] = s * apk + c * aqk;
                }
                for (int k = 0; k < 4; ++k) {
                    float vkp = V[k][p], vkq = V[k][q];
                    V[k][p] = c * vkp - s * vkq;
                    V[k][q] = s * vkp + c * vkq;
                }
            }
        }
    }
}

#define FOR16(OP) OP(0) OP(1) OP(2) OP(3) OP(4) OP(5) OP(6) OP(7) \
                  OP(8) OP(9) OP(10) OP(11) OP(12) OP(13) OP(14) OP(15)

// 512 blocks x 256 threads, persistent (2 blocks/CU). Block handles 16 source
// points of batch b = bid>>8 (named-scalar registers); wave w scans target
// slice [w*1024,(w+1)*1024), one float4 target per lane per iter. Per step:
// NN -> striped agent atomics -> fence-free grid barrier -> every block
// redundantly gathers the slot sums + solves the 4x4 Kabsch eigenproblem
// (bit-identical across blocks).
__global__ __launch_bounds__(256, 2) void icp_main(
    const float* __restrict__ psrc, float* __restrict__ ws,
    float* __restrict__ out) {

    float* ptgt4 = ws;
    float* acc = ws + ACC_OFF;
    unsigned* ctrs = (unsigned*)(ws + CTR_OFF);
    unsigned* flag = ctrs + NSTEPS * 160;

    __shared__ float st[2][13];     // per batch: Rcum(9), tcum(3), err(1)
    __shared__ unsigned keys[4][16];
    __shared__ float red[16][16];
    __shared__ float asum[2][16];
    __shared__ float convs[2];

    const int tid = threadIdx.x;
    const int bid = blockIdx.x;
    const int b = bid >> 8;             // batch (256 blocks each)
    const int n0 = (bid & 255) * 16;    // this block's 16 source points

    if (tid < 2) {
        st[tid][0] = 1.f; st[tid][1] = 0.f; st[tid][2] = 0.f;
        st[tid][3] = 0.f; st[tid][4] = 1.f; st[tid][5] = 0.f;
        st[tid][6] = 0.f; st[tid][7] = 0.f; st[tid][8] = 1.f;
        st[tid][9] = 0.f; st[tid][10] = 0.f; st[tid][11] = 0.f;
        st[tid][12] = 0.f;
    }
    __syncthreads();

    const int w = tid >> 6, lane = tid & 63;
    const int m0 = w * 1024 + lane;
    const float4* tpb = (const float4*)ptgt4 + ((size_t)b * MPTS + m0);
    const float* ps = psrc + ((size_t)b * NPTS + n0) * 3;

    for (int step = 0; step < NSTEPS; ++step) {
        float R00 = st[b][0], R01 = st[b][1], R02 = st[b][2];
        float R10 = st[b][3], R11 = st[b][4], R12 = st[b][5];
        float R20 = st[b][6], R21 = st[b][7], R22 = st[b][8];
        float t0 = st[b][9], t1 = st[b][10], t2 = st[b][11];

        // 16 transformed source points in named registers
#define DECLP(i) float px##i, py##i, pz##i;
        FOR16(DECLP)
#undef DECLP
#define LOADP(i) { float x = ps[3*(i)], y = ps[3*(i)+1], z = ps[3*(i)+2]; \
        px##i = fmaf(R00, x, fmaf(R01, y, fmaf(R02, z, t0))); \
        py##i = fmaf(R10, x, fmaf(R11, y, fmaf(R12, z, t1))); \
        pz##i = fmaf(R20, x, fmaf(R21, y, fmaf(R22, z, t2))); }
        FOR16(LOADP)
#undef LOADP

        // s = p.t - |t|^2/2; argmax s == argmin dist (strict > keeps first max)
#define DECLB(i) float bs##i = -3.0e38f; int ix##i = m0;
        FOR16(DECLB)
#undef DECLB

        float4 tc0 = tpb[0];
        float4 tc1 = tpb[64];
        int mreg = m0;
#pragma unroll
        for (int k = 0; k < 16; ++k) {
            float4 tnx = tpb[((k + 2) & 15) * 64];  // wraps harmlessly
            float tx = tc0.x, ty = tc0.y, tz = tc0.z, htn = tc0.w;
#define PAIR(i) { float s = fmaf(px##i, tx, fmaf(py##i, ty, fmaf(pz##i, tz, -htn))); \
            if (s > bs##i) { bs##i = s; ix##i = mreg; } }
            FOR16(PAIR)
#undef PAIR
            mreg += 64;
            tc0 = tc1;
            tc1 = tnx;
        }

        // wave argmax via order-preserving packed key: score hi-20 | (4095-m)
#define REDKEY(i) { unsigned ub = __float_as_uint(bs##i); \
        unsigned u = ((int)ub >= 0) ? (ub | 0x80000000u) : ~ub; \
        unsigned key = (u & 0xFFFFF000u) | (4095u - (unsigned)ix##i); \
        for (int off = 32; off; off >>= 1) { \
            unsigned o = (unsigned)__shfl_xor((int)key, off); \
            key = key > o ? key : o; } \
        if (lane == 0) keys[w][i] = key; }
        FOR16(REDKEY)
#undef REDKEY
        __syncthreads();

        if (tid < 16) {
            unsigned key = keys[0][tid];
            unsigned k1 = keys[1][tid], k2 = keys[2][tid], k3 = keys[3][tid];
            key = key > k1 ? key : k1;
            key = key > k2 ? key : k2;
            key = key > k3 ? key : k3;
            int m = 4095 - (int)(key & 0xFFFu);
            float4 q = ((const float4*)ptgt4)[(size_t)b * MPTS + m];
            const float* pp = psrc + ((size_t)b * NPTS + n0 + tid) * 3;
            float x = pp[0], y = pp[1], z = pp[2];
            float px = fmaf(R00, x, fmaf(R01, y, fmaf(R02, z, t0)));
            float py = fmaf(R10, x, fmaf(R11, y, fmaf(R12, z, t1)));
            float pz = fmaf(R20, x, fmaf(R21, y, fmaf(R22, z, t2)));
            float dx = px - q.x, dy = py - q.y, dz = pz - q.z;
            float dist = sqrtf(dx * dx + dy * dy + dz * dz);
            red[tid][0] = px; red[tid][1] = py; red[tid][2] = pz;
            red[tid][3] = q.x; red[tid][4] = q.y; red[tid][5] = q.z;
            red[tid][6] = px * q.x;  red[tid][7] = px * q.y;  red[tid][8] = px * q.z;
            red[tid][9] = py * q.x;  red[tid][10] = py * q.y; red[tid][11] = py * q.z;
            red[tid][12] = pz * q.x; red[tid][13] = pz * q.y; red[tid][14] = pz * q.z;
            red[tid][15] = dist;
        }
        __syncthreads();
        if (tid < 16) {
            float s = 0.f;
#pragma unroll
            for (int r = 0; r < 16; ++r) s += red[r][tid];
            // striped: each block adds into slot (bid&31) -> 32 distinct lines/batch
            atomicAdd(&acc[(((size_t)step * 2 + b) * NSLOT + (bid & (NSLOT - 1))) * 16 + tid], s);
        }

        grid_barrier(ctrs + step * 160, flag, (unsigned)(step + 1), bid);

        // ---- gather slot sums (32 threads), then redundant per-block Kabsch ----
        if (tid < 32) {
            int bb = tid >> 4, c = tid & 15;
            const float* base = acc + (((size_t)step * 2 + bb) * NSLOT) * 16 + c;
            float s = 0.f;
#pragma unroll
            for (int sl = 0; sl < NSLOT; ++sl)
                s += __hip_atomic_load(base + sl * 16, __ATOMIC_RELAXED,
                                       __HIP_MEMORY_SCOPE_AGENT);
            asum[bb][c] = s;
        }
        __syncthreads();

        float a[16];
        float errnew = 0.f;
        if (tid < 2) {
            for (int i = 0; i < 16; ++i) a[i] = asum[tid][i];
            errnew = a[15] * (1.f / NPTS);
            convs[tid] = (fabsf(errnew - st[tid][12]) < ICP_TOL) ? 1.f : 0.f;
        }
        __syncthreads();
        bool done_new = (convs[0] != 0.f) && (convs[1] != 0.f);

        if (tid < 2 && !done_new) {
            const float inv_n = 1.f / NPTS;
            float pmx = a[0] * inv_n, pmy = a[1] * inv_n, pmz = a[2] * inv_n;
            float qmx = a[3] * inv_n, qmy = a[4] * inv_n, qmz = a[5] * inv_n;
            float H[3][3];
            for (int i = 0; i < 3; ++i)
                for (int j = 0; j < 3; ++j)
                    H[i][j] = a[6 + 3 * i + j] - a[i] * a[3 + j] * inv_n;

            float Sxx = H[0][0], Sxy = H[0][1], Sxz = H[0][2];
            float Syx = H[1][0], Syy = H[1][1], Syz = H[1][2];
            float Szx = H[2][0], Szy = H[2][1], Szz = H[2][2];

            float A[4][4];
            A[0][0] = Sxx + Syy + Szz;
            A[0][1] = Syz - Szy;
            A[0][2] = Szx - Sxz;
            A[0][3] = Sxy - Syx;
            A[1][1] = Sxx - Syy - Szz;
            A[1][2] = Sxy + Syx;
            A[1][3] = Szx + Sxz;
            A[2][2] = -Sxx + Syy - Szz;
            A[2][3] = Syz + Szy;
            A[3][3] = -Sxx - Syy + Szz;
            A[1][0] = A[0][1]; A[2][0] = A[0][2]; A[3][0] = A[0][3];
            A[2][1] = A[1][2]; A[3][1] = A[1][3]; A[3][2] = A[2][3];

            float V[4][4];
            jacobi4(A, V);
            int bi = 0;
            float bv = A[0][0];
            for (int i = 1; i < 4; ++i)
                if (A[i][i] > bv) { bv = A[i][i]; bi = i; }
            float qw = V[0][bi], qx = V[1][bi], qy = V[2][bi], qz = V[3][bi];
            float nr = frsq(qw * qw + qx * qx + qy * qy + qz * qz);
            qw *= nr; qx *= nr; qy *= nr; qz *= nr;

            float R00n = 1.f - 2.f * (qy * qy + qz * qz);
            float R01n = 2.f * (qx * qy - qw * qz);
            float R02n = 2.f * (qx * qz + qw * qy);
            float R10n = 2.f * (qx * qy + qw * qz);
            float R11n = 1.f - 2.f * (qx * qx + qz * qz);
            float R12n = 2.f * (qy * qz - qw * qx);
            float R20n = 2.f * (qx * qz - qw * qy);
            float R21n = 2.f * (qy * qz + qw * qx);
            float R22n = 1.f - 2.f * (qx * qx + qy * qy);

            float tx = qmx - (R00n * pmx + R01n * pmy + R02n * pmz);
            float ty = qmy - (R10n * pmx + R11n * pmy + R12n * pmz);
            float tz = qmz - (R20n * pmx + R21n * pmy + R22n * pmz);

            float C00 = st[tid][0], C01 = st[tid][1], C02 = st[tid][2];
            float C10 = st[tid][3], C11 = st[tid][4], C12 = st[tid][5];
            float C20 = st[tid][6], C21 = st[tid][7], C22 = st[tid][8];
            float T0 = st[tid][9], T1 = st[tid][10], T2 = st[tid][11];

            st[tid][0] = R00n * C00 + R01n * C10 + R02n * C20;
            st[tid][1] = R00n * C01 + R01n * C11 + R02n * C21;
            st[tid][2] = R00n * C02 + R01n * C12 + R02n * C22;
            st[tid][3] = R10n * C00 + R11n * C10 + R12n * C20;
            st[tid][4] = R10n * C01 + R11n * C11 + R12n * C21;
            st[tid][5] = R10n * C02 + R11n * C12 + R12n * C22;
            st[tid][6] = R20n * C00 + R21n * C10 + R22n * C20;
            st[tid][7] = R20n * C01 + R21n * C11 + R22n * C21;
            st[tid][8] = R20n * C02 + R21n * C12 + R22n * C22;
            st[tid][9]  = R00n * T0 + R01n * T1 + R02n * T2 + tx;
            st[tid][10] = R10n * T0 + R11n * T1 + R12n * T2 + ty;
            st[tid][11] = R20n * T0 + R21n * T1 + R22n * T2 + tz;
            st[tid][12] = errnew;
        }
        __syncthreads();
        if (done_new) break;   // bit-identical decision across all blocks
    }

    if (bid == 0 && tid < 2) {
        float r00 = st[tid][0], r01 = st[tid][1], r02 = st[tid][2];
        float r10 = st[tid][3], r11 = st[tid][4], r12 = st[tid][5];
        float r20 = st[tid][6], r21 = st[tid][7], r22 = st[tid][8];
        float qw = 0.5f * sqrtf(fmaxf(1.f + r00 + r11 + r22, 1e-12f));
        float qx = 0.5f * sqrtf(fmaxf(1.f + r00 - r11 - r22, 1e-12f));
        float qy = 0.5f * sqrtf(fmaxf(1.f - r00 + r11 - r22, 1e-12f));
        float qz = 0.5f * sqrtf(fmaxf(1.f - r00 - r11 + r22, 1e-12f));
        qx = (r21 - r12 >= 0.f) ? qx : -qx;
        qy = (r02 - r20 >= 0.f) ? qy : -qy;
        qz = (r10 - r01 >= 0.f) ? qz : -qz;
        out[tid * 7 + 0] = st[tid][9];
        out[tid * 7 + 1] = st[tid][10];
        out[tid * 7 + 2] = st[tid][11];
        out[tid * 7 + 3] = qx;
        out[tid * 7 + 4] = qy;
        out[tid * 7 + 5] = qz;
        out[tid * 7 + 6] = qw;
    }
}

extern "C" void kernel_launch(void* const* d_in, const int* in_sizes, int n_in,
                              void* d_out, int out_size, void* d_ws, size_t ws_size,
                              hipStream_t stream) {
    const float* psrc = (const float*)d_in[0];
    const float* ptgt = (const float*)d_in[1];
    float* out = (float*)d_out;
    float* ws = (float*)d_ws;

    init_kernel<<<32, 256, 0, stream>>>(ptgt, ws);
    icp_main<<<NBLK, 256, 0, stream>>>(psrc, ws, out);
}